// Round 9
// baseline (104.563 us; speedup 1.0000x reference)
//
#include <hip/hip_runtime.h>

// Fused MLPKAN, round 13 — batch-paired packed-f32 inner loop.
// Evidence chain: r11 instrumented (REPEAT=3, VALUBusy 73%) => L0 VALU-issue
// bound at ~20 VALU/batch; waste = per-j broadcast movs (xd/mm0/mm1) + pk/
// scalar ping-pong. r12 scalar (12/batch floor) unresolvable via dur_us
// (noise +-6us, kernel hides under 40us fills).
// Fix: pack TWO BATCHES per v2f instead of the H=2 dim:
//   - x-pairs come pre-paired from ds_read_b128 (consecutive b);
//   - accumulators are pairs;
//   - ALL splats are weight-derived, loop-invariant per ii -> hoisted out of
//     the 16-j loop; LLVM emits v_pk_fma_f32 (gfx90a+) for v2f fma, and
//     member-wise v_max_f32 needs no movs (pair halves are plain VGPRs).
//   => 8 pk_fma + <=8 max per j-pair = <=8 VALU/batch (worst case: scalar
//      floor 12). Same repack in layer 1.
// Skeleton (staging, hp partials, combine, op, store, 1-deep weight
// prefetch) = r0 verbatim; flat code (r11 verified no hidden LDS).
// Predict: kernel ~34 -> ~21-24us; dur_us ~88-97; absmax 0.0625.

typedef float v2f __attribute__((ext_vector_type(2)));

#define BATCH 16384
#define TB    32

__global__ __launch_bounds__(512, 4) void kan_fused8(
    const float* __restrict__ x,
    const float* __restrict__ A1, const float* __restrict__ a1,
    const float* __restrict__ A2, const float* __restrict__ a2,
    const float* __restrict__ A3, const float* __restrict__ a3,
    const float* __restrict__ B1, const float* __restrict__ c1,
    const float* __restrict__ B2, const float* __restrict__ c2,
    const float* __restrict__ B3, const float* __restrict__ c3,
    float* __restrict__ out)
{
    __shared__ float xs[64][36];        // x transposed: xs[i][b]
    __shared__ float hp[4][TB][64];     // layer0 partials per i-quarter
    __shared__ float ht[64][36];        // h transposed: ht[i][b]
    __shared__ float op[4][TB][16];     // layer1 partials per i-quarter

    const int t    = threadIdx.x;
    const int lane = t & 63;
    const int wave = t >> 6;            // 0..7
    const int iq   = wave & 3;          // i-quarter: [16*iq, 16*iq+16)
    const int bh   = wave >> 2;         // batch-half: [16*bh, 16*bh+16)
    const int bB0  = blockIdx.x * TB;

    // ---- stage x transposed: 2048 floats, 512 thr x float4 ----
    {
        const int k = t * 4;
        const float4 v = *(const float4*)(x + (long)bB0 * 64 + k);
        const int b = k >> 6, i = k & 63;
        xs[i][b] = v.x; xs[i + 1][b] = v.y; xs[i + 2][b] = v.z; xs[i + 3][b] = v.w;
    }
    __syncthreads();

    const v2f zz = {0.f, 0.f};
    const int boff = 16 * bh;

    // ================= layer 0: 64 -> 64 =================
    {
        const int o  = lane;
        const int i0 = 16 * iq;

        v2f acc2[8];                    // 8 batch-pairs
#pragma unroll
        for (int q = 0; q < 8; ++q) acc2[q] = zz;
        float bsum = 0.f;

        float2 w1, d1, d2, w3; float4 w2; float b3v;
        {
            const int n = (i0 << 6) + o;
            w1  = *(const float2*)(A1 + 2 * n);
            d1  = *(const float2*)(a1 + 2 * n);
            w2  = *(const float4*)(A2 + 4 * n);
            d2  = *(const float2*)(a2 + 2 * n);
            w3  = *(const float2*)(A3 + 2 * n);
            b3v = a3[n];
        }

#pragma unroll 1
        for (int ii = 0; ii < 16; ++ii) {
            const int i = i0 + ii;
            float2 nw1, nd1, nd2, nw3; float4 nw2; float nb3;
            {
                const int n = ((i0 + ((ii + 1) & 15)) << 6) + o;
                nw1 = *(const float2*)(A1 + 2 * n);
                nd1 = *(const float2*)(a1 + 2 * n);
                nw2 = *(const float4*)(A2 + 4 * n);
                nd2 = *(const float2*)(a2 + 2 * n);
                nw3 = *(const float2*)(A3 + 2 * n);
                nb3 = a3[n];
            }

            const float4 xv0 = *(const float4*)&xs[i][boff];          // ds b128
            const float4 xv1 = *(const float4*)&xs[i][boff + 4];
            const float4 xv2 = *(const float4*)&xs[i][boff + 8];
            const float4 xv3 = *(const float4*)&xs[i][boff + 12];
            const float4 xv[4] = {xv0, xv1, xv2, xv3};
            const v2f* xp = (const v2f*)xv;                           // 8 pairs

            bsum += b3v;
            // loop-invariant weight splats (hoisted out of the j-loop)
            const v2f w1x = {w1.x, w1.x}, w1y = {w1.y, w1.y};
            const v2f d1x = {d1.x, d1.x}, d1y = {d1.y, d1.y};
            const v2f w2x = {w2.x, w2.x}, w2y = {w2.y, w2.y};
            const v2f w2z = {w2.z, w2.z}, w2w = {w2.w, w2.w};
            const v2f d2x = {d2.x, d2.x}, d2y = {d2.y, d2.y};
            const v2f w3x = {w3.x, w3.x}, w3y = {w3.y, w3.y};

#pragma unroll
            for (int q = 0; q < 8; ++q) {
                v2f ma = __builtin_elementwise_fma(xp[q], w1x, d1x);  // h1a pair
                v2f mb = __builtin_elementwise_fma(xp[q], w1y, d1y);  // h1b pair
                ma = __builtin_elementwise_max(ma, zz);
                mb = __builtin_elementwise_max(mb, zz);
                v2f ta = __builtin_elementwise_fma(ma, w2x, d2x);     // h2a pair
                ta = __builtin_elementwise_fma(mb, w2y, ta);
                v2f tb = __builtin_elementwise_fma(ma, w2z, d2y);     // h2b pair
                tb = __builtin_elementwise_fma(mb, w2w, tb);
                ta = __builtin_elementwise_max(ta, zz);
                tb = __builtin_elementwise_max(tb, zz);
                acc2[q] = __builtin_elementwise_fma(ta, w3x, acc2[q]);
                acc2[q] = __builtin_elementwise_fma(tb, w3y, acc2[q]);
            }
            w1 = nw1; d1 = nd1; w2 = nw2; d2 = nd2; w3 = nw3; b3v = nb3;
        }

#pragma unroll
        for (int q = 0; q < 8; ++q) {
            hp[iq][boff + 2 * q][o]     = acc2[q].x + bsum;   // 2-way, free
            hp[iq][boff + 2 * q + 1][o] = acc2[q].y + bsum;
        }
    }
    __syncthreads();

    // ---- combine i-quarters + transpose: ht[i][b] = sum_q hp[q][b][i] ----
    for (int k = t; k < TB * 64; k += 512) {
        const int b = k >> 6, i = k & 63;
        ht[i][b] = hp[0][b][i] + hp[1][b][i] + hp[2][b][i] + hp[3][b][i];
    }
    __syncthreads();

    // ================= layer 1: 64 -> 16 =================
    {
        const int o1 = lane & 15;
        const int ig = lane >> 4;          // 4 i-subgroups of 4
        const int i0 = 16 * iq + 4 * ig;

        v2f acc2[8];
#pragma unroll
        for (int q = 0; q < 8; ++q) acc2[q] = zz;
        float bsum = 0.f;

        float2 w1, d1, d2, w3; float4 w2; float b3v;
        {
            const int n = (i0 << 4) + o1;
            w1  = *(const float2*)(B1 + 2 * n);
            d1  = *(const float2*)(c1 + 2 * n);
            w2  = *(const float4*)(B2 + 4 * n);
            d2  = *(const float2*)(c2 + 2 * n);
            w3  = *(const float2*)(B3 + 2 * n);
            b3v = c3[n];
        }

#pragma unroll 1
        for (int ii = 0; ii < 4; ++ii) {
            const int i = i0 + ii;
            float2 nw1, nd1, nd2, nw3; float4 nw2; float nb3;
            {
                const int n = ((i0 + ((ii + 1) & 3)) << 4) + o1;
                nw1 = *(const float2*)(B1 + 2 * n);
                nd1 = *(const float2*)(c1 + 2 * n);
                nw2 = *(const float4*)(B2 + 4 * n);
                nd2 = *(const float2*)(c2 + 2 * n);
                nw3 = *(const float2*)(B3 + 2 * n);
                nb3 = c3[n];
            }

            const float4 hv0 = *(const float4*)&ht[i][boff];
            const float4 hv1 = *(const float4*)&ht[i][boff + 4];
            const float4 hv2 = *(const float4*)&ht[i][boff + 8];
            const float4 hv3 = *(const float4*)&ht[i][boff + 12];
            const float4 hv[4] = {hv0, hv1, hv2, hv3};
            const v2f* xp = (const v2f*)hv;

            bsum += b3v;
            const v2f w1x = {w1.x, w1.x}, w1y = {w1.y, w1.y};
            const v2f d1x = {d1.x, d1.x}, d1y = {d1.y, d1.y};
            const v2f w2x = {w2.x, w2.x}, w2y = {w2.y, w2.y};
            const v2f w2z = {w2.z, w2.z}, w2w = {w2.w, w2.w};
            const v2f d2x = {d2.x, d2.x}, d2y = {d2.y, d2.y};
            const v2f w3x = {w3.x, w3.x}, w3y = {w3.y, w3.y};

#pragma unroll
            for (int q = 0; q < 8; ++q) {
                v2f ma = __builtin_elementwise_fma(xp[q], w1x, d1x);
                v2f mb = __builtin_elementwise_fma(xp[q], w1y, d1y);
                ma = __builtin_elementwise_max(ma, zz);
                mb = __builtin_elementwise_max(mb, zz);
                v2f ta = __builtin_elementwise_fma(ma, w2x, d2x);
                ta = __builtin_elementwise_fma(mb, w2y, ta);
                v2f tb = __builtin_elementwise_fma(ma, w2z, d2y);
                tb = __builtin_elementwise_fma(mb, w2w, tb);
                ta = __builtin_elementwise_max(ta, zz);
                tb = __builtin_elementwise_max(tb, zz);
                acc2[q] = __builtin_elementwise_fma(ta, w3x, acc2[q]);
                acc2[q] = __builtin_elementwise_fma(tb, w3y, acc2[q]);
            }
            w1 = nw1; d1 = nd1; w2 = nw2; d2 = nd2; w3 = nw3; b3v = nb3;
        }

        // reduce over ig (lanes 16 apart), write per-iq partial
#pragma unroll
        for (int q = 0; q < 8; ++q) {
#pragma unroll
            for (int h = 0; h < 2; ++h) {
                float v = (h ? acc2[q].y : acc2[q].x) + bsum;
                v += __shfl_xor(v, 16, 64);
                v += __shfl_xor(v, 32, 64);
                if (ig == 0) op[iq][boff + 2 * q + h][o1] = v;
            }
        }
    }
    __syncthreads();

    // ---- store: out = sum_q op[q], 512 floats, float4 coalesced ----
    if (t < 128) {
        const int f = t * 4;
        const float4 p0 = *(const float4*)(&op[0][0][0] + f);
        const float4 p1 = *(const float4*)(&op[1][0][0] + f);
        const float4 p2 = *(const float4*)(&op[2][0][0] + f);
        const float4 p3 = *(const float4*)(&op[3][0][0] + f);
        float4 r;
        r.x = p0.x + p1.x + p2.x + p3.x;
        r.y = p0.y + p1.y + p2.y + p3.y;
        r.z = p0.z + p1.z + p2.z + p3.z;
        r.w = p0.w + p1.w + p2.w + p3.w;
        *(float4*)(out + (long)bB0 * 16 + f) = r;
    }
}

extern "C" void kernel_launch(void* const* d_in, const int* in_sizes, int n_in,
                              void* d_out, int out_size, void* d_ws, size_t ws_size,
                              hipStream_t stream) {
    const float* x     = (const float*)d_in[0];
    const float* l0_W1 = (const float*)d_in[1];
    const float* l0_b1 = (const float*)d_in[2];
    const float* l0_W2 = (const float*)d_in[3];
    const float* l0_b2 = (const float*)d_in[4];
    const float* l0_W3 = (const float*)d_in[5];
    const float* l0_b3 = (const float*)d_in[6];
    const float* l1_W1 = (const float*)d_in[7];
    const float* l1_b1 = (const float*)d_in[8];
    const float* l1_W2 = (const float*)d_in[9];
    const float* l1_b2 = (const float*)d_in[10];
    const float* l1_W3 = (const float*)d_in[11];
    const float* l1_b3 = (const float*)d_in[12];

    float* outp = (float*)d_out;

    dim3 blk(512);
    dim3 grid(BATCH / TB);   // 512 blocks, 2 per CU
    hipLaunchKernelGGL(kan_fused8, grid, blk, 0, stream,
                       x,
                       l0_W1, l0_b1, l0_W2, l0_b2, l0_W3, l0_b3,
                       l1_W1, l1_b1, l1_W2, l1_b2, l1_W3, l1_b3,
                       outp);
}